// Round 7
// baseline (266.507 us; speedup 1.0000x reference)
//
#include <hip/hip_runtime.h>

// B=8, T=2048, C=768, H=64. x fp32 [B,T,C]; Wq/Wk/Wv fp32 [C,H]; out fp32 [B,T,H].
// R16: finalize merged into attn via split-k last-block reduction — each (b,qs)
//      group of 4 quarter-blocks bumps a device-scope atomic counter after its
//      partial-O/l stores (+threadfence release); the 4th block re-reads the 4
//      partials and writes final out (bit-identical summation order to the old
//      finalize kernel). Counters zeroed by wt_kernel each launch (ws is
//      re-poisoned between iterations). Removes 1 launch + 1 full-device drain.
//      qkv/wt bodies and attn main loop unchanged from R15 (117.2 us).

typedef __bf16 bf16x8 __attribute__((ext_vector_type(8)));
typedef float  f32x4  __attribute__((ext_vector_type(4)));
typedef unsigned int u32;

union ABu {
    bf16x8 v;
    uint4  u;
    unsigned short us[8];
};

__device__ __forceinline__ unsigned short f2bf(float f) {
    union { __bf16 h; unsigned short s; } c;
    c.h = (__bf16)f;          // RNE
    return c.s;
}
__device__ __forceinline__ float bf2f(unsigned short s) {
    union { unsigned int u; float f; } c; c.u = ((unsigned int)s) << 16;
    return c.f;
}
// packed fp32x2 -> bf16x2 (RNE), low half = lo
__device__ __forceinline__ u32 cvtpk_bf16(float lo, float hi) {
    u32 r;
    asm("v_cvt_pk_bf16_f32 %0, %1, %2" : "=v"(r) : "v"(lo), "v"(hi));
    return r;
}

// async global->LDS, 16B per lane; dst must be wave-uniform base + lane*16
__device__ __forceinline__ void gld16(void* lds, const void* g) {
    __builtin_amdgcn_global_load_lds(
        (const u32 __attribute__((address_space(1)))*)g,
        (u32 __attribute__((address_space(3)))*)lds, 16, 0, 0);
}

// ---------------------------------------------------------------------------
// Kernel 1: W [768][64] fp32 -> wF fragment-major bf16. Also zeroes the
// split-k counters (ws is re-poisoned between iterations).
// ---------------------------------------------------------------------------
__global__ __launch_bounds__(256)
void wt_kernel(const float* __restrict__ Wq, const float* __restrict__ Wk,
               const float* __restrict__ Wv, unsigned short* __restrict__ wF,
               int* __restrict__ cnt) {
    const int t = threadIdx.x;
    if (blockIdx.x == 0) cnt[t] = 0;          // 256 counters: (b*32 + qs)
    const int j   = blockIdx.x / 6;
    const int kgg = blockIdx.x % 6;
    const int kg = kgg * 4 + (t >> 6);
    const int lane = t & 63, quad = lane >> 4, l16 = lane & 15;
    const int m = j >> 2, nb = (j & 3) * 16;
    const float* W = (m == 0) ? Wq : (m == 1) ? Wk : Wv;
    ABu o;
#pragma unroll
    for (int i = 0; i < 8; ++i)
        o.us[i] = f2bf(W[(kg * 32 + quad * 8 + i) * 64 + nb + l16]);
    *(uint4*)(wF + ((size_t)(j * 24 + kg) * 64 + lane) * 8) = o.u;
}

// ---------------------------------------------------------------------------
// Kernel 2: QKV GEMM, double-buffered. 512 blocks x 512 threads (8 waves).
// x staged in LDS as bf16 (single conversion at staging). LDS 70.3 KB -> 2/CU.
// ---------------------------------------------------------------------------
__global__ __launch_bounds__(512, 4)
void qkv_kernel(const float* __restrict__ x, const unsigned short* __restrict__ wF,
                unsigned short* __restrict__ qF, unsigned short* __restrict__ kF,
                unsigned short* __restrict__ vF) {
    __shared__ unsigned short xs[2][32][72];          // 9.2 KB bf16 (144B rows, 16B-aligned)
    __shared__ unsigned short wsW[2][24][64][8];      // 48 KB
    __shared__ unsigned short Cst[2][12][16][17];     // 13.1 KB
    const int tid  = threadIdx.x;
    const int lane = tid & 63, w = tid >> 6;
    const int l16  = lane & 15, quad = lane >> 4;
    const int mh   = w & 1, nh = w >> 1;
    const int m0   = blockIdx.x * 32;
    const int b    = m0 >> 11;

    f32x4 acc[3];
#pragma unroll
    for (int j = 0; j < 3; ++j) acc[j] = (f32x4){0.f, 0.f, 0.f, 0.f};

    const int xrow = tid >> 4, xc16 = tid & 15;       // 512 thr = 32 rows x 16 float4

    // prologue: stage iter 0 into buffer 0
#pragma unroll
    for (int i = 0; i < 3; ++i) {
        const int c = w * 3 + i, j = c >> 1, kg2 = c & 1;
        gld16((char*)wsW[0] + (size_t)c * 1024 + lane * 16,
              (const char*)wF + ((size_t)(j * 24 + kg2) * 64 + lane) * 16);
    }
    {
        float4 xv = *(const float4*)&x[(size_t)(m0 + xrow) * 768 + xc16 * 4];
        *(uint2*)&xs[0][xrow][xc16 * 4] =
            (uint2){cvtpk_bf16(xv.x, xv.y), cvtpk_bf16(xv.z, xv.w)};
    }
    __syncthreads();

    for (int kk = 0; kk < 12; ++kk) {
        const int cur = kk & 1, nxt = cur ^ 1;
        float4 xn;
        if (kk + 1 < 12) {
            // prefetch next W slice (async -> LDS) and next x tile (-> regs)
#pragma unroll
            for (int i = 0; i < 3; ++i) {
                const int c = w * 3 + i, j = c >> 1, kg2 = c & 1;
                gld16((char*)wsW[nxt] + (size_t)c * 1024 + lane * 16,
                      (const char*)wF + ((size_t)(j * 24 + (kk + 1) * 2 + kg2) * 64 + lane) * 16);
            }
            xn = *(const float4*)&x[(size_t)(m0 + xrow) * 768 + (kk + 1) * 64 + xc16 * 4];
        }

        // compute current buffer: A-frag is a single b128 LDS read (bf16)
#pragma unroll
        for (int kg2 = 0; kg2 < 2; ++kg2) {
            ABu af;
            af.u = *(const uint4*)&xs[cur][mh * 16 + l16][kg2 * 32 + quad * 8];
#pragma unroll
            for (int jl = 0; jl < 3; ++jl) {
                const int j = nh * 3 + jl;
                ABu bf;
                bf.u = *(const uint4*)((char*)wsW[cur] + (size_t)(j * 2 + kg2) * 1024 + lane * 16);
                acc[jl] = __builtin_amdgcn_mfma_f32_16x16x32_bf16(af.v, bf.v, acc[jl], 0, 0, 0);
            }
        }

        if (kk + 1 < 12)
            *(uint2*)&xs[nxt][xrow][xc16 * 4] =
                (uint2){cvtpk_bf16(xn.x, xn.y), cvtpk_bf16(xn.z, xn.w)};
        __syncthreads();   // drains prefetch; protects cur for next overwrite
    }

    // ---- epilogue: C-frags -> Cst (bf16) -> fragment-major stores ----
#pragma unroll
    for (int jl = 0; jl < 3; ++jl)
#pragma unroll
        for (int r = 0; r < 4; ++r)
            Cst[mh][nh * 3 + jl][quad * 4 + r][l16] = f2bf(acc[jl][r]);
    __syncthreads();

    const int g = tid >> 6, el = tid & 63;
    const int eq = el >> 4, e16 = el & 15;
    if (g < 4) {   // Q and K frags
        const int mhh = g >> 1, kg = g & 1;
        ABu oq, ok;
#pragma unroll
        for (int i = 0; i < 8; ++i) {
            const int h = kg * 32 + eq * 8 + i;
            oq.us[i] = Cst[mhh][h >> 4][e16][h & 15];
            ok.us[i] = Cst[mhh][4 + (h >> 4)][e16][h & 15];
        }
        const size_t tt = (size_t)b * 128 + ((m0 & 2047) >> 4) + mhh;
        *(uint4*)(qF + ((tt * 2 + kg) * 64 + el) * 8) = oq.u;
        *(uint4*)(kF + ((tt * 2 + kg) * 64 + el) * 8) = ok.u;
    } else {       // V frags
        const int nt = g & 3;
        const int sv = (m0 & 2047) >> 6, kg = (m0 >> 5) & 1;
        ABu ov;
#pragma unroll
        for (int i = 0; i < 8; ++i) {
            const int loc = eq * 8 + i;
            ov.us[i] = Cst[loc >> 4][8 + nt][loc & 15][e16];
        }
        *(uint4*)(vF + ((((size_t)(b * 32 + sv) * 4 + nt) * 2 + kg) * 64 + el) * 8) = ov.u;
    }
}

// ---------------------------------------------------------------------------
// Kernel 3: flash attention + fused split-k finalize. 1024 blocks x 256 thr.
// Swapped QK^T (S^T), in-register P transpose, mask only diagonal tile,
// row-sum via ones-MFMA, XCD-balanced mapping. Last quarter-block per (b,qs)
// reduces the 4 partials and writes final out.
// ---------------------------------------------------------------------------
template<bool MASKED>
__device__ __forceinline__ void attn_tile(
    const int st, const int b, const int tq0,
    const int lane, const int l16, const int quad,
    const ABu& aq0, const ABu& aq1, const ABu& onesb,
    const unsigned short* __restrict__ kF,
    const unsigned short* __restrict__ vF,
    f32x4 acc[4], f32x4& lacc)
{
    const float SC = 0.125f * 1.44269504089f;   // scale * log2(e)
    const float MB = 16.0f  * 1.44269504089f;   // fixed-max * log2(e)
    const int s0 = st * 64;
    const unsigned short* kbase = kF + (size_t)(b * 128 + st * 4) * 1024;
    const unsigned short* vbase = vF + (size_t)(b * 32 + st) * 4096;

    // issue all 16 K/V loads up front: V latency hides under QK^T + softmax
    ABu kf[8];
#pragma unroll
    for (int c = 0; c < 8; ++c)
        kf[c].u = *(const uint4*)(kbase + (size_t)c * 512 + lane * 8);
    ABu vf[8];
#pragma unroll
    for (int c = 0; c < 8; ++c)
        vf[c].u = *(const uint4*)(vbase + (size_t)c * 512 + lane * 8);

    float p[4][4];
#pragma unroll
    for (int nt = 0; nt < 4; ++nt) {
        f32x4 s = (f32x4){0.f, 0.f, 0.f, 0.f};
        // swapped operands: A = K-frag (rows = s), B = Q-frag (cols = q)
        s = __builtin_amdgcn_mfma_f32_16x16x32_bf16(kf[nt * 2 + 0].v, aq0.v, s, 0, 0, 0);
        s = __builtin_amdgcn_mfma_f32_16x16x32_bf16(kf[nt * 2 + 1].v, aq1.v, s, 0, 0, 0);
#pragma unroll
        for (int r = 0; r < 4; ++r) {
            float pv = __builtin_amdgcn_exp2f(__builtin_fmaf(s[r], SC, -MB));
            if (MASKED)
                pv = (s0 + nt * 16 + quad * 4 + r > tq0 + l16) ? 0.f : pv;
            p[nt][r] = pv;
        }
    }

    // P (S^T C-layout) -> PV A-frags, fully in-register.
    // af[ks].us[j] = P[q=l16][s = ks*32 + quad*8 + j].
    ABu af[2];
#pragma unroll
    for (int ks = 0; ks < 2; ++ks) {
        u32 x0 = cvtpk_bf16(p[2 * ks][0], p[2 * ks][1]);
        u32 x1 = cvtpk_bf16(p[2 * ks][2], p[2 * ks][3]);
        u32 y0 = cvtpk_bf16(p[2 * ks + 1][0], p[2 * ks + 1][1]);
        u32 y1 = cvtpk_bf16(p[2 * ks + 1][2], p[2 * ks + 1][3]);
        asm("v_permlane32_swap_b32 %0, %1" : "+v"(x0), "+v"(y0));
        asm("v_permlane16_swap_b32 %0, %1" : "+v"(x0), "+v"(y0));
        asm("v_permlane32_swap_b32 %0, %1" : "+v"(x1), "+v"(y1));
        asm("v_permlane16_swap_b32 %0, %1" : "+v"(x1), "+v"(y1));
        af[ks].u = (uint4){x0, x1, y0, y1};
    }

#pragma unroll
    for (int nt = 0; nt < 4; ++nt) {
        acc[nt] = __builtin_amdgcn_mfma_f32_16x16x32_bf16(af[0].v, vf[nt * 2 + 0].v, acc[nt], 0, 0, 0);
        acc[nt] = __builtin_amdgcn_mfma_f32_16x16x32_bf16(af[1].v, vf[nt * 2 + 1].v, acc[nt], 0, 0, 0);
    }
    // row-sum of (rounded) P via ones-MFMA: lacc[r] = l[q], all cols equal
    lacc = __builtin_amdgcn_mfma_f32_16x16x32_bf16(af[0].v, onesb.v, lacc, 0, 0, 0);
    lacc = __builtin_amdgcn_mfma_f32_16x16x32_bf16(af[1].v, onesb.v, lacc, 0, 0, 0);
}

__global__ __launch_bounds__(256, 2)
void attn_kernel(const unsigned short* __restrict__ qF,
                 const unsigned short* __restrict__ kF,
                 const unsigned short* __restrict__ vF,
                 unsigned short* __restrict__ opart, float* __restrict__ lpart,
                 int* __restrict__ cnt, float* __restrict__ out) {
    __shared__ int s_old;
    const int tid  = threadIdx.x;
    const int lane = tid & 63, w = tid >> 6;
    const int l16  = lane & 15, quad = lane >> 4;
    const int idx  = blockIdx.x;
    // XCD-balanced mapping: XCD = idx&7 -> batch b (K/V slice L2-resident);
    // hi -> (quarter, qs) such that co-resident blocks mix heavy/light rows.
    const int b    = idx & 7;
    const int hi   = idx >> 3;               // 0..127
    const int quarter = hi & 3;
    const int g    = (hi >> 2) & 7;
    const int tr   = hi >> 5;                // 0..3
    const int v    = g + ((tr >> 1) << 3);
    const int qs   = (tr & 1) ? (31 - v) : v;
    const int tt   = qs * 4 + w;
    const int tq0  = tt * 16;

    ABu aq0, aq1, onesb;
    aq0.u = *(const uint4*)(qF + ((((size_t)b * 128 + tt) * 2 + 0) * 64 + lane) * 8);
    aq1.u = *(const uint4*)(qF + ((((size_t)b * 128 + tt) * 2 + 1) * 64 + lane) * 8);
    onesb.u = (uint4){0x3F803F80u, 0x3F803F80u, 0x3F803F80u, 0x3F803F80u};  // bf16 1.0 x8

    f32x4 acc[4];
#pragma unroll
    for (int nt = 0; nt < 4; ++nt) acc[nt] = (f32x4){0.f, 0.f, 0.f, 0.f};
    f32x4 lacc = (f32x4){0.f, 0.f, 0.f, 0.f};

    int st = quarter;
    for (; st < qs; st += 4)
        attn_tile<false>(st, b, tq0, lane, l16, quad, aq0, aq1, onesb, kF, vF, acc, lacc);
    if (st == qs)
        attn_tile<true>(st, b, tq0, lane, l16, quad, aq0, aq1, onesb, kF, vF, acc, lacc);

    // ---- partial stores: bf16 partial-O, fp32 partial-l ----
    unsigned short* obase = opart + ((size_t)(quarter * 8 + b) * 2048 + tq0) * 64;
#pragma unroll
    for (int nt = 0; nt < 4; ++nt)
#pragma unroll
        for (int r = 0; r < 4; ++r)
            obase[(size_t)(quad * 4 + r) * 64 + nt * 16 + l16] = f2bf(acc[nt][r]);
    if (l16 == 0) {
#pragma unroll
        for (int r = 0; r < 4; ++r)
            lpart[(size_t)(quarter * 8 + b) * 2048 + tq0 + quad * 4 + r] = lacc[r];
    }

    // ---- split-k: 4th quarter-block of (b,qs) reduces and writes out ----
    __threadfence();                          // release partials device-wide
    __syncthreads();
    if (tid == 0) s_old = atomicAdd(&cnt[b * 32 + qs], 1);
    __syncthreads();
    if (s_old == 3) {
        __threadfence();                      // acquire partners' partials
        const int r  = tid >> 2;              // 0..63 (row within qs block)
        const int cg = (tid & 3) * 16;        // col group
        const int t  = qs * 64 + r;
        float l = 0.f;
#pragma unroll
        for (int q = 0; q < 4; ++q) l += lpart[(size_t)(q * 8 + b) * 2048 + t];
        const float li = 1.f / l;
        float s[16];
#pragma unroll
        for (int i = 0; i < 16; ++i) s[i] = 0.f;
#pragma unroll
        for (int q = 0; q < 4; ++q) {
            const unsigned short* pp = opart + ((size_t)(q * 8 + b) * 2048 + t) * 64 + cg;
            uint4 u0 = *(const uint4*)pp;
            uint4 u1 = *(const uint4*)(pp + 8);
            const unsigned short* us0 = (const unsigned short*)&u0;
            const unsigned short* us1 = (const unsigned short*)&u1;
#pragma unroll
            for (int i = 0; i < 8; ++i) {
                s[i]     += bf2f(us0[i]);
                s[8 + i] += bf2f(us1[i]);
            }
        }
        float* op = out + ((size_t)b * 2048 + t) * 64 + cg;
#pragma unroll
        for (int i = 0; i < 16; ++i) s[i] *= li;
#pragma unroll
        for (int i = 0; i < 4; ++i)
            *(float4*)(op + i * 4) = (float4){s[i * 4], s[i * 4 + 1], s[i * 4 + 2], s[i * 4 + 3]};
    }
}

// ---------------------------------------------------------------------------
extern "C" void kernel_launch(void* const* d_in, const int* in_sizes, int n_in,
                              void* d_out, int out_size, void* d_ws, size_t ws_size,
                              hipStream_t stream) {
    const float* x  = (const float*)d_in[0];
    const float* Wq = (const float*)d_in[1];
    const float* Wk = (const float*)d_in[2];
    const float* Wv = (const float*)d_in[3];
    float* out = (float*)d_out;

    char* ws = (char*)d_ws;
    unsigned short* wF    = (unsigned short*)ws;                              // 288 KB
    unsigned short* qF    = (unsigned short*)(ws + (512 << 10));              // 2 MB
    unsigned short* kF    = (unsigned short*)(ws + (512 << 10) + (2 << 20));  // 2 MB
    unsigned short* vF    = (unsigned short*)(ws + (512 << 10) + (4 << 20));  // 2 MB
    unsigned short* opart = (unsigned short*)(ws + (512 << 10) + (6 << 20));  // 8 MB bf16
    float*          lpart = (float*)(ws + (512 << 10) + (14 << 20));          // 256 KB
    int*            cnt   = (int*)(ws + (512 << 10) + (14 << 20) + (256 << 10)); // 1 KB

    wt_kernel<<<72, 256, 0, stream>>>(Wq, Wk, Wv, wF, cnt);
    qkv_kernel<<<512, 512, 0, stream>>>(x, wF, qF, kF, vF);
    attn_kernel<<<1024, 256, 0, stream>>>(qF, kF, vF, opart, lpart, cnt, out);
}

// Round 8
// 114.349 us; speedup vs baseline: 2.3306x; 2.3306x over previous
//
#include <hip/hip_runtime.h>

// B=8, T=2048, C=768, H=64. x fp32 [B,T,C]; Wq/Wk/Wv fp32 [C,H]; out fp32 [B,T,H].
// R17: revert R16's split-k fusion (device-scope threadfence per block = L2
//      writeback storm on 8 non-coherent XCD L2s; attn went 98%-stalled).
//      Back to R15's 4-kernel structure (117.2 us) + qkv occupancy push:
//      single-buffered W stage (24 KB, two barriers/iter), epilogue Cst
//      aliased into the dead wsW buffer, LDS 70.3 -> 33 KB, launch_bounds
//      (512,8) -> 4 blocks/CU (32 waves, CU max) to hide the exposed W-fetch
//      latency and barrier drains. attn/wt/finalize identical to R15.

typedef __bf16 bf16x8 __attribute__((ext_vector_type(8)));
typedef float  f32x4  __attribute__((ext_vector_type(4)));
typedef unsigned int u32;

union ABu {
    bf16x8 v;
    uint4  u;
    unsigned short us[8];
};

__device__ __forceinline__ unsigned short f2bf(float f) {
    union { __bf16 h; unsigned short s; } c;
    c.h = (__bf16)f;          // RNE
    return c.s;
}
__device__ __forceinline__ float bf2f(unsigned short s) {
    union { unsigned int u; float f; } c; c.u = ((unsigned int)s) << 16;
    return c.f;
}
// packed fp32x2 -> bf16x2 (RNE), low half = lo
__device__ __forceinline__ u32 cvtpk_bf16(float lo, float hi) {
    u32 r;
    asm("v_cvt_pk_bf16_f32 %0, %1, %2" : "=v"(r) : "v"(lo), "v"(hi));
    return r;
}

// async global->LDS, 16B per lane; dst must be wave-uniform base + lane*16
__device__ __forceinline__ void gld16(void* lds, const void* g) {
    __builtin_amdgcn_global_load_lds(
        (const u32 __attribute__((address_space(1)))*)g,
        (u32 __attribute__((address_space(3)))*)lds, 16, 0, 0);
}

// ---------------------------------------------------------------------------
// Kernel 1: W [768][64] fp32 -> wF fragment-major bf16.
// ---------------------------------------------------------------------------
__global__ __launch_bounds__(256)
void wt_kernel(const float* __restrict__ Wq, const float* __restrict__ Wk,
               const float* __restrict__ Wv, unsigned short* __restrict__ wF) {
    const int j   = blockIdx.x / 6;
    const int kgg = blockIdx.x % 6;
    const int t = threadIdx.x;
    const int kg = kgg * 4 + (t >> 6);
    const int lane = t & 63, quad = lane >> 4, l16 = lane & 15;
    const int m = j >> 2, nb = (j & 3) * 16;
    const float* W = (m == 0) ? Wq : (m == 1) ? Wk : Wv;
    ABu o;
#pragma unroll
    for (int i = 0; i < 8; ++i)
        o.us[i] = f2bf(W[(kg * 32 + quad * 8 + i) * 64 + nb + l16]);
    *(uint4*)(wF + ((size_t)(j * 24 + kg) * 64 + lane) * 8) = o.u;
}

// ---------------------------------------------------------------------------
// Kernel 2: QKV GEMM. 512 blocks x 512 threads (8 waves). Single-buffered W
// stage (24 KB), double-buffered bf16 x tile (9.2 KB); epilogue Cst aliases
// wsW. LDS 33 KB + launch_bounds(512,8) -> 4 blocks/CU.
// Loop: compute(Wk slice) -> bar1 -> gld16 next slice + x-store -> bar2.
// ---------------------------------------------------------------------------
__global__ __launch_bounds__(512, 8)
void qkv_kernel(const float* __restrict__ x, const unsigned short* __restrict__ wF,
                unsigned short* __restrict__ qF, unsigned short* __restrict__ kF,
                unsigned short* __restrict__ vF) {
    __shared__ unsigned short xs[2][32][72];          // 9.2 KB bf16 (144B rows)
    __shared__ unsigned short wsW[24][64][8];         // 24 KB, single buffer
    const int tid  = threadIdx.x;
    const int lane = tid & 63, w = tid >> 6;
    const int l16  = lane & 15, quad = lane >> 4;
    const int mh   = w & 1, nh = w >> 1;
    const int m0   = blockIdx.x * 32;
    const int b    = m0 >> 11;

    f32x4 acc[3];
#pragma unroll
    for (int j = 0; j < 3; ++j) acc[j] = (f32x4){0.f, 0.f, 0.f, 0.f};

    const int xrow = tid >> 4, xc16 = tid & 15;       // 512 thr = 32 rows x 16 float4

    // prologue: stage W slice 0 + x tile 0
#pragma unroll
    for (int i = 0; i < 3; ++i) {
        const int c = w * 3 + i, j = c >> 1, kg2 = c & 1;
        gld16((char*)wsW + (size_t)c * 1024 + lane * 16,
              (const char*)wF + ((size_t)(j * 24 + kg2) * 64 + lane) * 16);
    }
    {
        float4 xv = *(const float4*)&x[(size_t)(m0 + xrow) * 768 + xc16 * 4];
        *(uint2*)&xs[0][xrow][xc16 * 4] =
            (uint2){cvtpk_bf16(xv.x, xv.y), cvtpk_bf16(xv.z, xv.w)};
    }
    __syncthreads();

    for (int kk = 0; kk < 12; ++kk) {
        const int cur = kk & 1, nxt = cur ^ 1;
        float4 xn;
        if (kk + 1 < 12)   // issue next x row load early (hides under compute)
            xn = *(const float4*)&x[(size_t)(m0 + xrow) * 768 + (kk + 1) * 64 + xc16 * 4];

        // compute current W slice; A-frag is a single b128 LDS read (bf16)
#pragma unroll
        for (int kg2 = 0; kg2 < 2; ++kg2) {
            ABu af;
            af.u = *(const uint4*)&xs[cur][mh * 16 + l16][kg2 * 32 + quad * 8];
#pragma unroll
            for (int jl = 0; jl < 3; ++jl) {
                const int j = nh * 3 + jl;
                ABu bf;
                bf.u = *(const uint4*)((char*)wsW + (size_t)(j * 2 + kg2) * 1024 + lane * 16);
                acc[jl] = __builtin_amdgcn_mfma_f32_16x16x32_bf16(af.v, bf.v, acc[jl], 0, 0, 0);
            }
        }

        __syncthreads();                         // bar1: all wsW reads done
        if (kk + 1 < 12) {
#pragma unroll
            for (int i = 0; i < 3; ++i) {        // overwrite wsW with next slice
                const int c = w * 3 + i, j = c >> 1, kg2 = c & 1;
                gld16((char*)wsW + (size_t)c * 1024 + lane * 16,
                      (const char*)wF + ((size_t)(j * 24 + (kk + 1) * 2 + kg2) * 64 + lane) * 16);
            }
            *(uint2*)&xs[nxt][xrow][xc16 * 4] =
                (uint2){cvtpk_bf16(xn.x, xn.y), cvtpk_bf16(xn.z, xn.w)};
            __syncthreads();                     // bar2: gld16 + x-store landed
        }
    }

    // ---- epilogue: C-frags -> Cst (bf16, aliased onto dead wsW) ----
    unsigned short (*Cst)[12][16][17] =
        (unsigned short (*)[12][16][17])(&wsW[0][0][0]);   // 13.1 KB < 24 KB
#pragma unroll
    for (int jl = 0; jl < 3; ++jl)
#pragma unroll
        for (int r = 0; r < 4; ++r)
            Cst[mh][nh * 3 + jl][quad * 4 + r][l16] = f2bf(acc[jl][r]);
    __syncthreads();

    const int g = tid >> 6, el = tid & 63;
    const int eq = el >> 4, e16 = el & 15;
    if (g < 4) {   // Q and K frags
        const int mhh = g >> 1, kg = g & 1;
        ABu oq, ok;
#pragma unroll
        for (int i = 0; i < 8; ++i) {
            const int h = kg * 32 + eq * 8 + i;
            oq.us[i] = Cst[mhh][h >> 4][e16][h & 15];
            ok.us[i] = Cst[mhh][4 + (h >> 4)][e16][h & 15];
        }
        const size_t tt = (size_t)b * 128 + ((m0 & 2047) >> 4) + mhh;
        *(uint4*)(qF + ((tt * 2 + kg) * 64 + el) * 8) = oq.u;
        *(uint4*)(kF + ((tt * 2 + kg) * 64 + el) * 8) = ok.u;
    } else {       // V frags
        const int nt = g & 3;
        const int sv = (m0 & 2047) >> 6, kg = (m0 >> 5) & 1;
        ABu ov;
#pragma unroll
        for (int i = 0; i < 8; ++i) {
            const int loc = eq * 8 + i;
            ov.us[i] = Cst[loc >> 4][8 + nt][loc & 15][e16];
        }
        *(uint4*)(vF + ((((size_t)(b * 32 + sv) * 4 + nt) * 2 + kg) * 64 + el) * 8) = ov.u;
    }
}

// ---------------------------------------------------------------------------
// Kernel 3: flash attention, barrier-free, zero-LDS. 1024 blocks x 256 thr.
// Swapped QK^T (S^T), in-register P transpose, mask only diagonal tile,
// row-sum via ones-MFMA, XCD-balanced (b, qs, quarter) mapping. (R15 body.)
// ---------------------------------------------------------------------------
template<bool MASKED>
__device__ __forceinline__ void attn_tile(
    const int st, const int b, const int tq0,
    const int lane, const int l16, const int quad,
    const ABu& aq0, const ABu& aq1, const ABu& onesb,
    const unsigned short* __restrict__ kF,
    const unsigned short* __restrict__ vF,
    f32x4 acc[4], f32x4& lacc)
{
    const float SC = 0.125f * 1.44269504089f;   // scale * log2(e)
    const float MB = 16.0f  * 1.44269504089f;   // fixed-max * log2(e)
    const int s0 = st * 64;
    const unsigned short* kbase = kF + (size_t)(b * 128 + st * 4) * 1024;
    const unsigned short* vbase = vF + (size_t)(b * 32 + st) * 4096;

    // issue all 16 K/V loads up front: V latency hides under QK^T + softmax
    ABu kf[8];
#pragma unroll
    for (int c = 0; c < 8; ++c)
        kf[c].u = *(const uint4*)(kbase + (size_t)c * 512 + lane * 8);
    ABu vf[8];
#pragma unroll
    for (int c = 0; c < 8; ++c)
        vf[c].u = *(const uint4*)(vbase + (size_t)c * 512 + lane * 8);

    float p[4][4];
#pragma unroll
    for (int nt = 0; nt < 4; ++nt) {
        f32x4 s = (f32x4){0.f, 0.f, 0.f, 0.f};
        // swapped operands: A = K-frag (rows = s), B = Q-frag (cols = q)
        s = __builtin_amdgcn_mfma_f32_16x16x32_bf16(kf[nt * 2 + 0].v, aq0.v, s, 0, 0, 0);
        s = __builtin_amdgcn_mfma_f32_16x16x32_bf16(kf[nt * 2 + 1].v, aq1.v, s, 0, 0, 0);
#pragma unroll
        for (int r = 0; r < 4; ++r) {
            float pv = __builtin_amdgcn_exp2f(__builtin_fmaf(s[r], SC, -MB));
            if (MASKED)
                pv = (s0 + nt * 16 + quad * 4 + r > tq0 + l16) ? 0.f : pv;
            p[nt][r] = pv;
        }
    }

    // P (S^T C-layout) -> PV A-frags, fully in-register.
    // af[ks].us[j] = P[q=l16][s = ks*32 + quad*8 + j].
    ABu af[2];
#pragma unroll
    for (int ks = 0; ks < 2; ++ks) {
        u32 x0 = cvtpk_bf16(p[2 * ks][0], p[2 * ks][1]);
        u32 x1 = cvtpk_bf16(p[2 * ks][2], p[2 * ks][3]);
        u32 y0 = cvtpk_bf16(p[2 * ks + 1][0], p[2 * ks + 1][1]);
        u32 y1 = cvtpk_bf16(p[2 * ks + 1][2], p[2 * ks + 1][3]);
        asm("v_permlane32_swap_b32 %0, %1" : "+v"(x0), "+v"(y0));
        asm("v_permlane16_swap_b32 %0, %1" : "+v"(x0), "+v"(y0));
        asm("v_permlane32_swap_b32 %0, %1" : "+v"(x1), "+v"(y1));
        asm("v_permlane16_swap_b32 %0, %1" : "+v"(x1), "+v"(y1));
        af[ks].u = (uint4){x0, x1, y0, y1};
    }

#pragma unroll
    for (int nt = 0; nt < 4; ++nt) {
        acc[nt] = __builtin_amdgcn_mfma_f32_16x16x32_bf16(af[0].v, vf[nt * 2 + 0].v, acc[nt], 0, 0, 0);
        acc[nt] = __builtin_amdgcn_mfma_f32_16x16x32_bf16(af[1].v, vf[nt * 2 + 1].v, acc[nt], 0, 0, 0);
    }
    // row-sum of (rounded) P via ones-MFMA: lacc[r] = l[q], all cols equal
    lacc = __builtin_amdgcn_mfma_f32_16x16x32_bf16(af[0].v, onesb.v, lacc, 0, 0, 0);
    lacc = __builtin_amdgcn_mfma_f32_16x16x32_bf16(af[1].v, onesb.v, lacc, 0, 0, 0);
}

__global__ __launch_bounds__(256, 2)
void attn_kernel(const unsigned short* __restrict__ qF,
                 const unsigned short* __restrict__ kF,
                 const unsigned short* __restrict__ vF,
                 unsigned short* __restrict__ opart, float* __restrict__ lpart) {
    const int tid  = threadIdx.x;
    const int lane = tid & 63, w = tid >> 6;
    const int l16  = lane & 15, quad = lane >> 4;
    const int idx  = blockIdx.x;
    // XCD-balanced mapping: XCD = idx&7 -> batch b (K/V slice L2-resident);
    // hi -> (quarter, qs) such that co-resident blocks mix heavy/light rows.
    const int b    = idx & 7;
    const int hi   = idx >> 3;               // 0..127
    const int quarter = hi & 3;
    const int g    = (hi >> 2) & 7;
    const int tr   = hi >> 5;                // 0..3
    const int v    = g + ((tr >> 1) << 3);
    const int qs   = (tr & 1) ? (31 - v) : v;
    const int tt   = qs * 4 + w;
    const int tq0  = tt * 16;

    ABu aq0, aq1, onesb;
    aq0.u = *(const uint4*)(qF + ((((size_t)b * 128 + tt) * 2 + 0) * 64 + lane) * 8);
    aq1.u = *(const uint4*)(qF + ((((size_t)b * 128 + tt) * 2 + 1) * 64 + lane) * 8);
    onesb.u = (uint4){0x3F803F80u, 0x3F803F80u, 0x3F803F80u, 0x3F803F80u};  // bf16 1.0 x8

    f32x4 acc[4];
#pragma unroll
    for (int nt = 0; nt < 4; ++nt) acc[nt] = (f32x4){0.f, 0.f, 0.f, 0.f};
    f32x4 lacc = (f32x4){0.f, 0.f, 0.f, 0.f};

    int st = quarter;
    for (; st < qs; st += 4)
        attn_tile<false>(st, b, tq0, lane, l16, quad, aq0, aq1, onesb, kF, vF, acc, lacc);
    if (st == qs)
        attn_tile<true>(st, b, tq0, lane, l16, quad, aq0, aq1, onesb, kF, vF, acc, lacc);

    // ---- epilogue: bf16 partial-O, fp32 partial-l ----
    unsigned short* obase = opart + ((size_t)(quarter * 8 + b) * 2048 + tq0) * 64;
#pragma unroll
    for (int nt = 0; nt < 4; ++nt)
#pragma unroll
        for (int r = 0; r < 4; ++r)
            obase[(size_t)(quad * 4 + r) * 64 + nt * 16 + l16] = f2bf(acc[nt][r]);
    if (l16 == 0) {
#pragma unroll
        for (int r = 0; r < 4; ++r)
            lpart[(size_t)(quarter * 8 + b) * 2048 + tq0 + quad * 4 + r] = lacc[r];
    }
}

// ---------------------------------------------------------------------------
// Kernel 4: finalize — out = (sum of 4 bf16 partial O) / (sum of 4 partial l).
// ---------------------------------------------------------------------------
__global__ __launch_bounds__(256)
void finalize_kernel(const unsigned short* __restrict__ opart,
                     const float* __restrict__ lpart, float* __restrict__ out) {
    const int idx = blockIdx.x * 256 + threadIdx.x;     // 4-elem group, 262144 total
    const int row = idx >> 4;
    float4 v = (float4){0.f, 0.f, 0.f, 0.f};
    float  l = 0.f;
#pragma unroll
    for (int q = 0; q < 4; ++q) {
        ushort4 u = ((const ushort4*)opart)[(size_t)q * 262144 + idx];
        v.x += bf2f(u.x); v.y += bf2f(u.y); v.z += bf2f(u.z); v.w += bf2f(u.w);
        l += lpart[(size_t)q * 16384 + row];
    }
    const float li = 1.f / l;
    v.x *= li; v.y *= li; v.z *= li; v.w *= li;
    ((float4*)out)[idx] = v;
}

// ---------------------------------------------------------------------------
extern "C" void kernel_launch(void* const* d_in, const int* in_sizes, int n_in,
                              void* d_out, int out_size, void* d_ws, size_t ws_size,
                              hipStream_t stream) {
    const float* x  = (const float*)d_in[0];
    const float* Wq = (const float*)d_in[1];
    const float* Wk = (const float*)d_in[2];
    const float* Wv = (const float*)d_in[3];
    float* out = (float*)d_out;

    char* ws = (char*)d_ws;
    unsigned short* wF    = (unsigned short*)ws;                              // 288 KB
    unsigned short* qF    = (unsigned short*)(ws + (512 << 10));              // 2 MB
    unsigned short* kF    = (unsigned short*)(ws + (512 << 10) + (2 << 20));  // 2 MB
    unsigned short* vF    = (unsigned short*)(ws + (512 << 10) + (4 << 20));  // 2 MB
    unsigned short* opart = (unsigned short*)(ws + (512 << 10) + (6 << 20));  // 8 MB bf16
    float*          lpart = (float*)(ws + (512 << 10) + (14 << 20));          // 256 KB

    wt_kernel<<<72, 256, 0, stream>>>(Wq, Wk, Wv, wF);
    qkv_kernel<<<512, 512, 0, stream>>>(x, wF, qF, kF, vF);
    attn_kernel<<<1024, 256, 0, stream>>>(qF, kF, vF, opart, lpart);
    finalize_kernel<<<1024, 256, 0, stream>>>(opart, lpart, out);
}